// Round 14
// baseline (5607.039 us; speedup 1.0000x reference)
//
#include <hip/hip_runtime.h>

#define VOCABN 401
#define EN 256
#define HN 768
#define H3N 2304
#define ON 3
#define BN 64
#define TN 1024

// 16 replicas x 16 WGs; WG = 768 threads = 12 waves = (wr:3 row-groups x wk:4 k-quarters).
// Pollers: tid<384. Gate threads: tid in [576,768). All waves do MFMA.
#define NREP 16
#define WGPR 16
#define BPR  4
#define JPW  48
#define NTH  768

typedef _Float16 f16x8 __attribute__((ext_vector_type(8)));
typedef float f32x4 __attribute__((ext_vector_type(4)));
typedef unsigned long long u64;

// workgroup barrier draining ONLY lgkm — in-flight global poll loads survive.
__device__ __forceinline__ void barrier_lgkm() {
    asm volatile("s_waitcnt lgkmcnt(0)\n\ts_barrier" ::: "memory");
}

// ---------------- K1: gtab[v][g] = dot(embed[v], W_ih[g]) + b_ih[g]  (w-stationary)
__global__ __launch_bounds__(256)
void k_build_gtab(const float* __restrict__ embed, const float* __restrict__ wih,
                  const float* __restrict__ bih, float* __restrict__ gtab) {
    const int g  = blockIdx.x * 64 + (threadIdx.x >> 2);
    const int ql = threadIdx.x & 3;
    const int v0 = blockIdx.y * 26;
    const int v1 = min(VOCABN, v0 + 26);
    float4 w[16];
    const float4* s4 = (const float4*)(wih + (size_t)g * EN + ql * 64);
#pragma unroll
    for (int i = 0; i < 16; ++i) w[i] = s4[i];
    const float bias = bih[g];
    for (int v = v0; v < v1; ++v) {
        const float4* e4 = (const float4*)(embed + (size_t)v * EN + ql * 64);
        float acc = 0.f;
#pragma unroll
        for (int i = 0; i < 16; ++i) {
            float4 e = e4[i];
            acc += w[i].x * e.x + w[i].y * e.y + w[i].z * e.z + w[i].w * e.w;
        }
        acc += __shfl_xor(acc, 1, 64);
        acc += __shfl_xor(acc, 2, 64);
        if (ql == 0) gtab[(size_t)v * H3N + g] = acc + bias;
    }
}

// ---------------- K2: persistent-weight recurrence; batch-staggered, MFMA engine,
// ONE lgkm-barrier per stage, gate lagged 2 stages (psum handoff across a barrier).
// Stage s (b=s&3, ts=s>>2), flattened s in [0, 4*TN+2):
//   pre-bar: [pollers: verify tile(ts,b) (first-try steady state), deposit to hT[b],
//             issue poll for stage s+1]  ||  [gate threads of batch gb=(s-2)&3:
//             reduce psum[gb] (written at stage s-2, barrier s-1 between), gates,
//             paired tagged store of h(tg+1,gb), x-prefetch]
//   bar(lgkm) | post-bar: all 12 waves: 18 MFMA on hT[b] -> psum[b].
// Safety: store of (t+1,b) at stage 4t+b+2 follows verify of tags stored by every
// peer at its stage 4t+b-1 > its read of (t-1,b) at stage 4t+b-4 (program order)
// -> overwrite safe. memset-0 == valid t=0 (tags 0, h=0). Agent-scope relaxed only.
__global__ __launch_bounds__(NTH, 1)
void k_rnn(const int* __restrict__ tokens, const float* __restrict__ whh,
           const float* __restrict__ gtab, const float* __restrict__ bhh,
           unsigned* __restrict__ hbuf, float* __restrict__ hout) {
    const int R    = blockIdx.x & (NREP - 1);
    const int wg   = blockIdx.x >> 4;
    const int tid  = threadIdx.x;
    const int lane = tid & 63;
    const int wave = tid >> 6;                 // 0..11
    const int wr   = wave % 3;                 // row-group (== gate index)
    const int wk   = wave / 3;                 // k-quarter
    const int koff8 = ((lane >> 4) & 3) * 8;
    const int kbase = wk * 192;

    __shared__ __align__(16) _Float16 hT[BPR][HN];     // 6144 B
    __shared__ __align__(16) float psum[BPR][4][144];  // [b][wk][row], 9216 B

    // ---- one-time: A fragments (m89-verified layout, r13-proven): lane holds
    // row = wr*48 + tt*16 + (lane&15), k = kbase + ks*32 + koff8 + i.
    f16x8 a[3][6];
#pragma unroll
    for (int tt = 0; tt < 3; ++tt) {
        const int lr  = wr * 48 + tt * 16 + (lane & 15);
        const int g   = lr / 48;
        const int jlr = lr % 48;
        const float* wsrc = whh + (size_t)(g * HN + wg * JPW + jlr) * HN;
#pragma unroll
        for (int ks = 0; ks < 6; ++ks) {
            const float4* p4 = (const float4*)(wsrc + kbase + ks * 32 + koff8);
            float4 x0 = p4[0], x1 = p4[1];
            f16x8 t;
            t[0] = (_Float16)x0.x; t[1] = (_Float16)x0.y;
            t[2] = (_Float16)x0.z; t[3] = (_Float16)x0.w;
            t[4] = (_Float16)x1.x; t[5] = (_Float16)x1.y;
            t[6] = (_Float16)x1.z; t[7] = (_Float16)x1.w;
            a[tt][ks] = t;
        }
    }

    u64* hb2 = (u64*)hbuf + (size_t)R * (2 * BPR * 384);

    // gate-thread persistent state (tid in [576,768)): owns (bown, jlown)
    const int gt    = tid - 576;
    const int bown  = (gt >= 0) ? gt / 48 : 0;
    const int jlown = (gt >= 0) ? gt - bown * 48 : 0;
    const int jown  = wg * JPW + jlown;
    float hprev = 0.f, xr = 0.f, xz = 0.f, xn = 0.f, bhr = 0.f, bhz = 0.f, bhn = 0.f;
    if (gt >= 0) {
        bhr = bhh[jown]; bhz = bhh[HN + jown]; bhn = bhh[2 * HN + jown];
        const int tok = tokens[(size_t)(R * BPR + bown) * TN + 0];
        const float* g_ = gtab + (size_t)tok * H3N;
        xr = g_[jown]; xz = g_[HN + jown]; xn = g_[2 * HN + jown];
    }

    // poll prologue: stage 0 = tile (0,0) at slot 0
    u64 vin = 0;
    if (tid < 384)
        vin = __hip_atomic_load(hb2 + tid, __ATOMIC_RELAXED, __HIP_MEMORY_SCOPE_AGENT);

    const int NSTG = TN * 4 + 2;
#pragma unroll 1
    for (int s = 0; s < NSTG; ++s) {
        const int b  = s & 3;
        const int ts = s >> 2;

        // ---- pre-barrier: pollers (verify + deposit + issue next poll)
        if (s < TN * 4 && tid < 384) {
            const u64 want = ((u64)(unsigned)ts << 16) | ((u64)(unsigned)ts << 48);
            const u64* cur = hb2 + ((ts & 1) * BPR + b) * 384 + tid;
            while ((vin & 0xFFFF0000FFFF0000ull) != want) {
                __builtin_amdgcn_s_sleep(1);
                vin = __hip_atomic_load(cur, __ATOMIC_RELAXED, __HIP_MEMORY_SCOPE_AGENT);
            }
            ((unsigned*)hT)[b * 384 + tid] =
                __builtin_amdgcn_perm((unsigned)(vin >> 32), (unsigned)vin, 0x05040100);
            const int s1 = s + 1;
            if (s1 < TN * 4) {
                const int b1 = s1 & 3, t1 = s1 >> 2;
                vin = __hip_atomic_load(hb2 + ((t1 & 1) * BPR + b1) * 384 + tid,
                                        __ATOMIC_RELAXED, __HIP_MEMORY_SCOPE_AGENT);
            }
        }
        // ---- pre-barrier: gate threads finish batch (s-2)&3
        if (gt >= 0 && s >= 2) {
            const int gs = s - 2, gb = gs & 3, tg = gs >> 2;
            if (bown == gb) {
                const float sr = (psum[gb][0][jlown]      + psum[gb][1][jlown])
                               + (psum[gb][2][jlown]      + psum[gb][3][jlown]);
                const float sz = (psum[gb][0][48 + jlown] + psum[gb][1][48 + jlown])
                               + (psum[gb][2][48 + jlown] + psum[gb][3][48 + jlown]);
                const float sn = (psum[gb][0][96 + jlown] + psum[gb][1][96 + jlown])
                               + (psum[gb][2][96 + jlown] + psum[gb][3][96 + jlown]);
                const float r  = 1.f / (1.f + __expf(-(xr + sr + bhr)));
                const float z  = 1.f / (1.f + __expf(-(xz + sz + bhz)));
                const float nx = xn + r * (sn + bhn);
                const float n  = 1.f - 2.f / (__expf(2.f * nx) + 1.f);   // tanh
                hprev = (1.f - z) * n + z * hprev;
                unsigned pk = ((unsigned)(tg + 1) << 16)
                    | (unsigned)__builtin_bit_cast(unsigned short, (_Float16)hprev);
                const unsigned pk2 = __shfl_down(pk, 1, 64);   // neighbor jlown+1
                if (tg < TN - 1) {
                    if (!(jlown & 1))
                        __hip_atomic_store(
                            hb2 + (((tg + 1) & 1) * BPR + gb) * 384 + wg * 24 + (jlown >> 1),
                            (u64)pk | ((u64)pk2 << 32),
                            __ATOMIC_RELAXED, __HIP_MEMORY_SCOPE_AGENT);
                    // x-gates for (tg+1, bown): consumed 4 stages later
                    const int tok = tokens[(size_t)(R * BPR + bown) * TN + (tg + 1)];
                    const float* g_ = gtab + (size_t)tok * H3N;
                    xr = g_[jown]; xz = g_[HN + jown]; xn = g_[2 * HN + jown];
                } else {
                    hout[(size_t)(R * BPR + bown) * HN + jown] = hprev;
                }
            }
        }
        barrier_lgkm();                        // tile b + psum handoff; polls in flight

        // ---- post-barrier: all 12 waves: 18 MFMA on tile b -> psum[b]
        if (s < TN * 4) {
            f32x4 acc0 = {0.f, 0.f, 0.f, 0.f};
            f32x4 acc1 = {0.f, 0.f, 0.f, 0.f};
            f32x4 acc2 = {0.f, 0.f, 0.f, 0.f};
#pragma unroll
            for (int ks = 0; ks < 6; ++ks) {
                f16x8 bf = *(const f16x8*)(&hT[b][kbase + ks * 32 + koff8]);
                acc0 = __builtin_amdgcn_mfma_f32_16x16x32_f16(a[0][ks], bf, acc0, 0, 0, 0);
                acc1 = __builtin_amdgcn_mfma_f32_16x16x32_f16(a[1][ks], bf, acc1, 0, 0, 0);
                acc2 = __builtin_amdgcn_mfma_f32_16x16x32_f16(a[2][ks], bf, acc2, 0, 0, 0);
            }
            if ((lane & 15) == 0) {            // D: col=lane&15, row=(lane>>4)*4+reg
                const int r0 = wr * 48 + (lane >> 4) * 4;
                *(f32x4*)&psum[b][wk][r0]      = acc0;
                *(f32x4*)&psum[b][wk][r0 + 16] = acc1;
                *(f32x4*)&psum[b][wk][r0 + 32] = acc2;
            }
        }
    }
}

// ---------------- K3: logits + log_softmax
__global__ void k_logits(const float* __restrict__ hfin, const float* __restrict__ wout,
                         const float* __restrict__ bout, float* __restrict__ lp) {
    const int b = blockIdx.x;
    const int o = threadIdx.x / 64;
    const int lane = threadIdx.x % 64;
    const float* hrow = hfin + (size_t)b * HN;
    const float* w = wout + (size_t)o * HN;
    float p = 0.f;
    for (int k = lane; k < HN; k += 64) p += hrow[k] * w[k];
    for (int off = 32; off > 0; off >>= 1) p += __shfl_down(p, off, 64);
    __shared__ float lg[ON];
    if (lane == 0) lg[o] = p + bout[o];
    __syncthreads();
    if (threadIdx.x == 0) {
        float m = fmaxf(lg[0], fmaxf(lg[1], lg[2]));
        float s = __expf(lg[0] - m) + __expf(lg[1] - m) + __expf(lg[2] - m);
        float ls = __logf(s);
        lp[b * ON + 0] = lg[0] - m - ls;
        lp[b * ON + 1] = lg[1] - m - ls;
        lp[b * ON + 2] = lg[2] - m - ls;
    }
}

extern "C" void kernel_launch(void* const* d_in, const int* in_sizes, int n_in,
                              void* d_out, int out_size, void* d_ws, size_t ws_size,
                              hipStream_t stream) {
    const int*   tokens = (const int*)d_in[0];
    // d_in[1] = hidden: reference zeroes it, ignored.
    const float* embed  = (const float*)d_in[2];
    const float* wih    = (const float*)d_in[3];
    const float* whh    = (const float*)d_in[4];
    const float* bih    = (const float*)d_in[5];
    const float* bhh    = (const float*)d_in[6];
    const float* wout   = (const float*)d_in[7];
    const float* bout   = (const float*)d_in[8];

    float* out = (float*)d_out;                  // [B*O logprobs][B*H h_final]
    char* ws = (char*)d_ws;
    const size_t GTAB_OFF = 0;                   // 401*2304*4 = 3,695,616
    const size_t HBUF_OFF = 3695616;             // 16*2*4*384*8 = 393,216 (tagged u64)
    float*    gtab = (float*)(ws + GTAB_OFF);
    unsigned* hbuf = (unsigned*)(ws + HBUF_OFF);

    // tag protocol requires tag==0 / h==0 state on EVERY launch (graph-replayed)
    hipMemsetAsync(ws + HBUF_OFF, 0, 393216, stream);

    hipLaunchKernelGGL(k_build_gtab, dim3(H3N / 64, 16), dim3(256), 0, stream,
                       embed, wih, bih, gtab);
    hipLaunchKernelGGL(k_rnn, dim3(NREP * WGPR), dim3(NTH), 0, stream,
                       tokens, whh, gtab, bhh, hbuf, out + BN * ON);
    hipLaunchKernelGGL(k_logits, dim3(BN), dim3(192), 0, stream,
                       out + BN * ON, wout, bout, out);
}

// Round 15
// 5588.848 us; speedup vs baseline: 1.0033x; 1.0033x over previous
//
#include <hip/hip_runtime.h>

#define VOCABN 401
#define EN 256
#define HN 768
#define H3N 2304
#define ON 3
#define BN 64
#define TN 1024

// 16 replicas x 16 WGs; WG = 768 threads = 12 waves = (wr:3 row-groups x wk:4 k-quarters).
// Pollers: tid<384. Gate threads: tid in [576,768). All waves do MFMA.
#define NREP 16
#define WGPR 16
#define BPR  4
#define JPW  48
#define NTH  768

typedef _Float16 f16x8 __attribute__((ext_vector_type(8)));
typedef float f32x4 __attribute__((ext_vector_type(4)));
typedef unsigned long long u64;

// workgroup barrier draining ONLY lgkm — in-flight global poll loads survive.
__device__ __forceinline__ void barrier_lgkm() {
    asm volatile("s_waitcnt lgkmcnt(0)\n\ts_barrier" ::: "memory");
}

// ---------------- K1: gtab[v][g] = dot(embed[v], W_ih[g]) + b_ih[g]  (w-stationary)
__global__ __launch_bounds__(256)
void k_build_gtab(const float* __restrict__ embed, const float* __restrict__ wih,
                  const float* __restrict__ bih, float* __restrict__ gtab) {
    const int g  = blockIdx.x * 64 + (threadIdx.x >> 2);
    const int ql = threadIdx.x & 3;
    const int v0 = blockIdx.y * 26;
    const int v1 = min(VOCABN, v0 + 26);
    float4 w[16];
    const float4* s4 = (const float4*)(wih + (size_t)g * EN + ql * 64);
#pragma unroll
    for (int i = 0; i < 16; ++i) w[i] = s4[i];
    const float bias = bih[g];
    for (int v = v0; v < v1; ++v) {
        const float4* e4 = (const float4*)(embed + (size_t)v * EN + ql * 64);
        float acc = 0.f;
#pragma unroll
        for (int i = 0; i < 16; ++i) {
            float4 e = e4[i];
            acc += w[i].x * e.x + w[i].y * e.y + w[i].z * e.z + w[i].w * e.w;
        }
        acc += __shfl_xor(acc, 1, 64);
        acc += __shfl_xor(acc, 2, 64);
        if (ql == 0) gtab[(size_t)v * H3N + g] = acc + bias;
    }
}

// ---------------- K2: persistent-weight recurrence; r14 skeleton (batch-stagger,
// one lgkm-barrier/stage, MFMA engine, gate lag 2) with LLC-direct transport:
// h-words move via sc0 sc1 loads/stores (proven r5/r6) — store->visible is
// store-at-LLC, no cross-XCD invalidation lag. Poll issued 1 stage ahead, drained
// at verify via vmcnt(0)+sched_barrier (rule #18). Tag protocol + anti-overwrite
// induction unchanged from r9-r14. memset-0 == valid t=0 state.
__global__ __launch_bounds__(NTH, 1)
void k_rnn(const int* __restrict__ tokens, const float* __restrict__ whh,
           const float* __restrict__ gtab, const float* __restrict__ bhh,
           unsigned* __restrict__ hbuf, float* __restrict__ hout) {
    const int R    = blockIdx.x & (NREP - 1);
    const int wg   = blockIdx.x >> 4;
    const int tid  = threadIdx.x;
    const int lane = tid & 63;
    const int wave = tid >> 6;                 // 0..11
    const int wr   = wave % 3;                 // row-group
    const int wk   = wave / 3;                 // k-quarter
    const int koff8 = ((lane >> 4) & 3) * 8;
    const int kbase = wk * 192;

    __shared__ __align__(16) _Float16 hT[BPR][HN];     // 6144 B
    __shared__ __align__(16) float psum[BPR][4][144];  // [b][wk][row], 9216 B

    // ---- one-time: A fragments (m89-verified layout, r13/r14-proven)
    f16x8 a[3][6];
#pragma unroll
    for (int tt = 0; tt < 3; ++tt) {
        const int lr  = wr * 48 + tt * 16 + (lane & 15);
        const int g   = lr / 48;
        const int jlr = lr % 48;
        const float* wsrc = whh + (size_t)(g * HN + wg * JPW + jlr) * HN;
#pragma unroll
        for (int ks = 0; ks < 6; ++ks) {
            const float4* p4 = (const float4*)(wsrc + kbase + ks * 32 + koff8);
            float4 x0 = p4[0], x1 = p4[1];
            f16x8 t;
            t[0] = (_Float16)x0.x; t[1] = (_Float16)x0.y;
            t[2] = (_Float16)x0.z; t[3] = (_Float16)x0.w;
            t[4] = (_Float16)x1.x; t[5] = (_Float16)x1.y;
            t[6] = (_Float16)x1.z; t[7] = (_Float16)x1.w;
            a[tt][ks] = t;
        }
    }

    u64* hb2 = (u64*)hbuf + (size_t)R * (2 * BPR * 384);

    // gate-thread persistent state (tid in [576,768)): owns (bown, jlown)
    const int gt    = tid - 576;
    const int bown  = (gt >= 0) ? gt / 48 : 0;
    const int jlown = (gt >= 0) ? gt - bown * 48 : 0;
    const int jown  = wg * JPW + jlown;
    float hprev = 0.f, xr = 0.f, xz = 0.f, xn = 0.f, bhr = 0.f, bhz = 0.f, bhn = 0.f;
    if (gt >= 0) {
        bhr = bhh[jown]; bhz = bhh[HN + jown]; bhn = bhh[2 * HN + jown];
        const int tok = tokens[(size_t)(R * BPR + bown) * TN + 0];
        const float* g_ = gtab + (size_t)tok * H3N;
        xr = g_[jown]; xz = g_[HN + jown]; xn = g_[2 * HN + jown];
    }

    // poll prologue: issue LLC-direct load for stage 0 (drained at its verify)
    u64 vin = 0;
    if (tid < 384)
        asm volatile("global_load_dwordx2 %0, %1, off sc0 sc1"
                     : "=v"(vin) : "v"(hb2 + tid) : "memory");

    const int NSTG = TN * 4 + 2;
#pragma unroll 1
    for (int s = 0; s < NSTG; ++s) {
        const int b  = s & 3;
        const int ts = s >> 2;

        // ---- pre-barrier: pollers (drain in-flight poll, verify, deposit, issue next)
        if (s < TN * 4 && tid < 384) {
            asm volatile("s_waitcnt vmcnt(0)" ::: "memory");
            __builtin_amdgcn_sched_barrier(0);
            const u64 want = ((u64)(unsigned)ts << 16) | ((u64)(unsigned)ts << 48);
            const u64* cur = hb2 + ((ts & 1) * BPR + b) * 384 + tid;
            while ((vin & 0xFFFF0000FFFF0000ull) != want) {
                asm volatile("global_load_dwordx2 %0, %1, off sc0 sc1\n\t"
                             "s_waitcnt vmcnt(0)"
                             : "=v"(vin) : "v"(cur) : "memory");
                __builtin_amdgcn_sched_barrier(0);
            }
            ((unsigned*)hT)[b * 384 + tid] =
                __builtin_amdgcn_perm((unsigned)(vin >> 32), (unsigned)vin, 0x05040100);
            const int s1 = s + 1;
            if (s1 < TN * 4) {
                const int b1 = s1 & 3, t1 = s1 >> 2;
                const u64* nxt = hb2 + ((t1 & 1) * BPR + b1) * 384 + tid;
                asm volatile("global_load_dwordx2 %0, %1, off sc0 sc1"
                             : "=v"(vin) : "v"(nxt) : "memory");
            }
        }
        // ---- pre-barrier: gate threads finish batch (s-2)&3
        if (gt >= 0 && s >= 2) {
            const int gs = s - 2, gb = gs & 3, tg = gs >> 2;
            if (bown == gb) {
                const float sr = (psum[gb][0][jlown]      + psum[gb][1][jlown])
                               + (psum[gb][2][jlown]      + psum[gb][3][jlown]);
                const float sz = (psum[gb][0][48 + jlown] + psum[gb][1][48 + jlown])
                               + (psum[gb][2][48 + jlown] + psum[gb][3][48 + jlown]);
                const float sn = (psum[gb][0][96 + jlown] + psum[gb][1][96 + jlown])
                               + (psum[gb][2][96 + jlown] + psum[gb][3][96 + jlown]);
                const float r  = 1.f / (1.f + __expf(-(xr + sr + bhr)));
                const float z  = 1.f / (1.f + __expf(-(xz + sz + bhz)));
                const float nx = xn + r * (sn + bhn);
                const float n  = 1.f - 2.f / (__expf(2.f * nx) + 1.f);   // tanh
                hprev = (1.f - z) * n + z * hprev;
                unsigned pk = ((unsigned)(tg + 1) << 16)
                    | (unsigned)__builtin_bit_cast(unsigned short, (_Float16)hprev);
                const unsigned pk2 = __shfl_down(pk, 1, 64);   // neighbor jlown+1
                if (tg < TN - 1) {
                    if (!(jlown & 1)) {
                        u64* dst = hb2 + (((tg + 1) & 1) * BPR + gb) * 384
                                 + wg * 24 + (jlown >> 1);
                        const u64 val = (u64)pk | ((u64)pk2 << 32);
                        asm volatile("global_store_dwordx2 %0, %1, off sc0 sc1"
                                     :: "v"(dst), "v"(val) : "memory");
                    }
                    // x-gates for (tg+1, bown): consumed 4 stages later
                    const int tok = tokens[(size_t)(R * BPR + bown) * TN + (tg + 1)];
                    const float* g_ = gtab + (size_t)tok * H3N;
                    xr = g_[jown]; xz = g_[HN + jown]; xn = g_[2 * HN + jown];
                } else {
                    hout[(size_t)(R * BPR + bown) * HN + jown] = hprev;
                }
            }
        }
        barrier_lgkm();                        // tile b + psum handoff; polls in flight

        // ---- post-barrier: all 12 waves: 18 MFMA on tile b -> psum[b]
        if (s < TN * 4) {
            f32x4 acc0 = {0.f, 0.f, 0.f, 0.f};
            f32x4 acc1 = {0.f, 0.f, 0.f, 0.f};
            f32x4 acc2 = {0.f, 0.f, 0.f, 0.f};
#pragma unroll
            for (int ks = 0; ks < 6; ++ks) {
                f16x8 bf = *(const f16x8*)(&hT[b][kbase + ks * 32 + koff8]);
                acc0 = __builtin_amdgcn_mfma_f32_16x16x32_f16(a[0][ks], bf, acc0, 0, 0, 0);
                acc1 = __builtin_amdgcn_mfma_f32_16x16x32_f16(a[1][ks], bf, acc1, 0, 0, 0);
                acc2 = __builtin_amdgcn_mfma_f32_16x16x32_f16(a[2][ks], bf, acc2, 0, 0, 0);
            }
            if ((lane & 15) == 0) {            // D: col=lane&15, row=(lane>>4)*4+reg
                const int r0 = wr * 48 + (lane >> 4) * 4;
                *(f32x4*)&psum[b][wk][r0]      = acc0;
                *(f32x4*)&psum[b][wk][r0 + 16] = acc1;
                *(f32x4*)&psum[b][wk][r0 + 32] = acc2;
            }
        }
    }
}

// ---------------- K3: logits + log_softmax
__global__ void k_logits(const float* __restrict__ hfin, const float* __restrict__ wout,
                         const float* __restrict__ bout, float* __restrict__ lp) {
    const int b = blockIdx.x;
    const int o = threadIdx.x / 64;
    const int lane = threadIdx.x % 64;
    const float* hrow = hfin + (size_t)b * HN;
    const float* w = wout + (size_t)o * HN;
    float p = 0.f;
    for (int k = lane; k < HN; k += 64) p += hrow[k] * w[k];
    for (int off = 32; off > 0; off >>= 1) p += __shfl_down(p, off, 64);
    __shared__ float lg[ON];
    if (lane == 0) lg[o] = p + bout[o];
    __syncthreads();
    if (threadIdx.x == 0) {
        float m = fmaxf(lg[0], fmaxf(lg[1], lg[2]));
        float s = __expf(lg[0] - m) + __expf(lg[1] - m) + __expf(lg[2] - m);
        float ls = __logf(s);
        lp[b * ON + 0] = lg[0] - m - ls;
        lp[b * ON + 1] = lg[1] - m - ls;
        lp[b * ON + 2] = lg[2] - m - ls;
    }
}

extern "C" void kernel_launch(void* const* d_in, const int* in_sizes, int n_in,
                              void* d_out, int out_size, void* d_ws, size_t ws_size,
                              hipStream_t stream) {
    const int*   tokens = (const int*)d_in[0];
    // d_in[1] = hidden: reference zeroes it, ignored.
    const float* embed  = (const float*)d_in[2];
    const float* wih    = (const float*)d_in[3];
    const float* whh    = (const float*)d_in[4];
    const float* bih    = (const float*)d_in[5];
    const float* bhh    = (const float*)d_in[6];
    const float* wout   = (const float*)d_in[7];
    const float* bout   = (const float*)d_in[8];

    float* out = (float*)d_out;                  // [B*O logprobs][B*H h_final]
    char* ws = (char*)d_ws;
    const size_t GTAB_OFF = 0;                   // 401*2304*4 = 3,695,616
    const size_t HBUF_OFF = 3695616;             // 16*2*4*384*8 = 393,216 (tagged u64)
    float*    gtab = (float*)(ws + GTAB_OFF);
    unsigned* hbuf = (unsigned*)(ws + HBUF_OFF);

    // tag protocol requires tag==0 / h==0 state on EVERY launch (graph-replayed)
    hipMemsetAsync(ws + HBUF_OFF, 0, 393216, stream);

    hipLaunchKernelGGL(k_build_gtab, dim3(H3N / 64, 16), dim3(256), 0, stream,
                       embed, wih, bih, gtab);
    hipLaunchKernelGGL(k_rnn, dim3(NREP * WGPR), dim3(NTH), 0, stream,
                       tokens, whh, gtab, bhh, hbuf, out + BN * ON);
    hipLaunchKernelGGL(k_logits, dim3(BN), dim3(192), 0, stream,
                       out + BN * ON, wout, bout, out);
}